// Round 1
// baseline (64.419 us; speedup 1.0000x reference)
//
#include <hip/hip_runtime.h>

// Problem constants
#define BB 8
#define FF 256
#define TT 1024
#define CC 64
constexpr float EPS = 1e-9f;

// ws layout (float offsets)
//  muT   : [F][C]         @ 0        (16384)
//  mu2   : [C]            @ 16384    (64)
//  x2    : [B][T]         @ 16448    (8192)
//  Nraw  : [B][C]         @ 24640    (512)
//  rws   : [B][C][T]      @ 25152    (524288)
//  fpart : [8][B][C][F]   @ 549440   (1048576)
#define WS_MUT   0
#define WS_MU2   16384
#define WS_X2    16448
#define WS_NRAW  24640
#define WS_R     25152
#define WS_FPART 549440

// ---------------------------------------------------------------------------
// Kernel 1: x2 row norms (blocks 0..31), muT + mu2 + Nraw zero (block 32)
// ---------------------------------------------------------------------------
__global__ __launch_bounds__(256) void prep_kernel(const float* __restrict__ x,
                                                   const float* __restrict__ mu,
                                                   float* __restrict__ ws) {
    float* muT  = ws + WS_MUT;
    float* mu2  = ws + WS_MU2;
    float* x2   = ws + WS_X2;
    float* Nraw = ws + WS_NRAW;
    const int bid = blockIdx.x, tid = threadIdx.x;
    if (bid < 32) {
        const int b = bid >> 2;
        const int t = ((bid & 3) << 8) + tid;
        const float* xp = x + b * FF * TT + t;
        float acc = 0.f;
        #pragma unroll 8
        for (int f = 0; f < FF; ++f) { float v = xp[f * TT]; acc += v * v; }
        x2[b * TT + t] = acc;
    } else {
        // transpose mu -> muT
        for (int it = 0; it < 64; ++it) {
            float v = mu[it * 256 + tid];   // c = it, f = tid
            muT[tid * 64 + it] = v;
        }
        if (tid < 64) {
            const float* mp = mu + tid * 256;
            float acc = 0.f;
            #pragma unroll 8
            for (int f = 0; f < 256; ++f) { float v = mp[f]; acc += v * v; }
            mu2[tid] = acc;
        }
        Nraw[tid] = 0.f;
        Nraw[tid + 256] = 0.f;
    }
}

// ---------------------------------------------------------------------------
// Kernel 2: per (b, 64-t tile): xmu GEMM, softmax over c, write r (B,C,T),
//           accumulate Nraw.
// Thread map: tc = tid&15 -> c = tc*4+j ; tg = tid>>4 -> t = t0 + tg*4+k
// ---------------------------------------------------------------------------
__global__ __launch_bounds__(256) void rsoft_kernel(const float* __restrict__ x,
                                                    const float* __restrict__ prec,
                                                    float* __restrict__ ws) {
    __shared__ float xs[16][64];    // [ff][t]
    __shared__ float ms[16][64];    // [ff][c]
    __shared__ float Sl[64][65];    // [t][c] (+pad)
    const float* muT = ws + WS_MUT;
    const float* mu2 = ws + WS_MU2;
    const float* x2  = ws + WS_X2;
    float* Nraw = ws + WS_NRAW;
    float* rws  = ws + WS_R;

    const int tid = threadIdx.x;
    const int b  = blockIdx.x >> 4;
    const int t0 = (blockIdx.x & 15) << 6;
    const int tc = tid & 15;        // c-group
    const int tg = tid >> 4;        // t-group

    float acc[4][4];                // acc[j][k]: c=tc*4+j, t=t0+tg*4+k
    #pragma unroll
    for (int j = 0; j < 4; ++j)
        #pragma unroll
        for (int k = 0; k < 4; ++k) acc[j][k] = 0.f;

    const float* xb = x + b * FF * TT;

    for (int cf = 0; cf < 16; ++cf) {
        const int ff0 = cf * 16;
        {   // cooperative load: ffL = tid>>4 (16 rows), txL = tid&15 (float4)
            const int ffL = tid >> 4, txL = tid & 15;
            float4 xv = *(const float4*)(xb + (ff0 + ffL) * TT + t0 + txL * 4);
            *(float4*)&xs[ffL][txL * 4] = xv;
            float4 mv = *(const float4*)(muT + (ff0 + ffL) * 64 + txL * 4);
            *(float4*)&ms[ffL][txL * 4] = mv;
        }
        __syncthreads();
        #pragma unroll
        for (int ff = 0; ff < 16; ++ff) {
            float xvk[4], mvj[4];
            *(float4*)xvk = *(float4*)&xs[ff][tg * 4];
            *(float4*)mvj = *(float4*)&ms[ff][tc * 4];
            #pragma unroll
            for (int j = 0; j < 4; ++j)
                #pragma unroll
                for (int k = 0; k < 4; ++k)
                    acc[j][k] += mvj[j] * xvk[k];
        }
        __syncthreads();
    }

    // llk = -prec^2 * (x2 - 2*xmu + mu2)
    float x2v[4], mu2v[4], p2v[4];
    #pragma unroll
    for (int k = 0; k < 4; ++k) x2v[k] = x2[b * TT + t0 + tg * 4 + k];
    #pragma unroll
    for (int j = 0; j < 4; ++j) {
        mu2v[j] = mu2[tc * 4 + j];
        float p = prec[tc * 4 + j];
        p2v[j] = p * p;
    }
    float rv[4][4];
    #pragma unroll
    for (int k = 0; k < 4; ++k) {
        float l[4];
        #pragma unroll
        for (int j = 0; j < 4; ++j)
            l[j] = -p2v[j] * (x2v[k] - 2.f * acc[j][k] + mu2v[j]);
        // softmax over the 64 c's: 4 regs x 16 lanes (lanes tc=0..15 in-group)
        float m = fmaxf(fmaxf(l[0], l[1]), fmaxf(l[2], l[3]));
        #pragma unroll
        for (int s = 1; s < 16; s <<= 1) m = fmaxf(m, __shfl_xor(m, s, 64));
        float e[4], sum = 0.f;
        #pragma unroll
        for (int j = 0; j < 4; ++j) { e[j] = __expf(l[j] - m); sum += e[j]; }
        #pragma unroll
        for (int s = 1; s < 16; s <<= 1) sum += __shfl_xor(sum, s, 64);
        const float inv = 1.f / sum;
        #pragma unroll
        for (int j = 0; j < 4; ++j) rv[j][k] = e[j] * inv;
    }

    // stage r into LDS [t][c]
    #pragma unroll
    for (int j = 0; j < 4; ++j)
        #pragma unroll
        for (int k = 0; k < 4; ++k)
            Sl[tg * 4 + k][tc * 4 + j] = rv[j][k];
    __syncthreads();

    // writeout (B,C,T) + Nraw column sums
    {
        const int c = tid >> 2, seg = tid & 3;
        float* dst = rws + (size_t)b * CC * TT + c * TT + t0 + seg * 16;
        float sum16 = 0.f;
        #pragma unroll
        for (int q = 0; q < 4; ++q) {
            float4 v;
            v.x = Sl[seg * 16 + q * 4 + 0][c];
            v.y = Sl[seg * 16 + q * 4 + 1][c];
            v.z = Sl[seg * 16 + q * 4 + 2][c];
            v.w = Sl[seg * 16 + q * 4 + 3][c];
            sum16 += v.x + v.y + v.z + v.w;
            *(float4*)(dst + q * 4) = v;
        }
        atomicAdd(&Nraw[b * CC + c], sum16);
    }
}

// ---------------------------------------------------------------------------
// Kernel 3: F_part[tchunk][b][c][f] = sum_{t in chunk} r[b][c][t] * x[b][f][t]
// grid 256: b(8) x ftile(4 of 64) x tchunk(8 of 128)
// Thread map: tf = tid&15 -> f = f0+tf*4+i ; cg = tid>>4 -> c = cg*4+j
// ---------------------------------------------------------------------------
__global__ __launch_bounds__(256) void fein_kernel(const float* __restrict__ x,
                                                   float* __restrict__ ws) {
    __shared__ float xs3[32][68];   // [t][f] (+pad)
    __shared__ float rs3[32][68];   // [t][c] (+pad)
    const float* rws = ws + WS_R;
    float* fpart = ws + WS_FPART;

    const int tid = threadIdx.x;
    const int bid = blockIdx.x;
    const int b   = bid >> 5;
    const int f0  = ((bid >> 3) & 3) << 6;
    const int tch = bid & 7;
    const int t0  = tch << 7;
    const int tf = tid & 15, cg = tid >> 4;

    float acc[4][4];                // acc[j][i]: c=cg*4+j, f=f0+tf*4+i
    #pragma unroll
    for (int j = 0; j < 4; ++j)
        #pragma unroll
        for (int i = 0; i < 4; ++i) acc[j][i] = 0.f;

    const float* xb = x + b * FF * TT;
    const float* rb = rws + (size_t)b * CC * TT;

    for (int sc = 0; sc < 4; ++sc) {
        const int tc0 = t0 + sc * 32;
        #pragma unroll
        for (int u = 0; u < 2; ++u) {
            const int id = tid * 2 + u;
            const int fid = id >> 3, tseg = id & 7;   // fid 0..63, tseg 0..7
            float4 xv = *(const float4*)(xb + (f0 + fid) * TT + tc0 + tseg * 4);
            xs3[tseg * 4 + 0][fid] = xv.x;
            xs3[tseg * 4 + 1][fid] = xv.y;
            xs3[tseg * 4 + 2][fid] = xv.z;
            xs3[tseg * 4 + 3][fid] = xv.w;
            float4 rv = *(const float4*)(rb + fid * TT + tc0 + tseg * 4);
            rs3[tseg * 4 + 0][fid] = rv.x;
            rs3[tseg * 4 + 1][fid] = rv.y;
            rs3[tseg * 4 + 2][fid] = rv.z;
            rs3[tseg * 4 + 3][fid] = rv.w;
        }
        __syncthreads();
        #pragma unroll 8
        for (int t = 0; t < 32; ++t) {
            float rvj[4], xvi[4];
            *(float4*)rvj = *(float4*)&rs3[t][cg * 4];
            *(float4*)xvi = *(float4*)&xs3[t][tf * 4];
            #pragma unroll
            for (int j = 0; j < 4; ++j)
                #pragma unroll
                for (int i = 0; i < 4; ++i)
                    acc[j][i] += rvj[j] * xvi[i];
        }
        __syncthreads();
    }

    float* fp = fpart + (size_t)tch * (BB * CC * FF) + b * (CC * FF);
    #pragma unroll
    for (int j = 0; j < 4; ++j) {
        float4 o = make_float4(acc[j][0], acc[j][1], acc[j][2], acc[j][3]);
        *(float4*)(fp + (cg * 4 + j) * FF + f0 + tf * 4) = o;
    }
}

// ---------------------------------------------------------------------------
// Kernel 4: reduce 8 partials, out = (F - Nraw*mu) / (Nraw + eps)
// ---------------------------------------------------------------------------
__global__ __launch_bounds__(256) void final_kernel(const float* __restrict__ mu,
                                                    const float* __restrict__ ws,
                                                    float* __restrict__ out) {
    const float* Nraw  = ws + WS_NRAW;
    const float* fpart = ws + WS_FPART;
    const int idx4 = (blockIdx.x * 256 + threadIdx.x) * 4;   // over B*C*F=131072
    const int b = idx4 >> 14;
    const int rem = idx4 & 16383;
    const int c = rem >> 8;
    float sx = 0.f, sy = 0.f, sz = 0.f, sw = 0.f;
    #pragma unroll
    for (int p = 0; p < 8; ++p) {
        float4 v = *(const float4*)(fpart + (size_t)p * (BB * CC * FF) + idx4);
        sx += v.x; sy += v.y; sz += v.z; sw += v.w;
    }
    const float nr = Nraw[b * CC + c];
    float4 m = *(const float4*)(mu + rem);   // rem = c*256+f
    const float inv = 1.f / (nr + EPS);
    float4 o;
    o.x = (sx - nr * m.x) * inv;
    o.y = (sy - nr * m.y) * inv;
    o.z = (sz - nr * m.z) * inv;
    o.w = (sw - nr * m.w) * inv;
    *(float4*)(out + idx4) = o;
}

extern "C" void kernel_launch(void* const* d_in, const int* in_sizes, int n_in,
                              void* d_out, int out_size, void* d_ws, size_t ws_size,
                              hipStream_t stream) {
    const float* x    = (const float*)d_in[0];
    const float* mu   = (const float*)d_in[1];
    const float* prec = (const float*)d_in[2];
    float* out = (float*)d_out;
    float* ws  = (float*)d_ws;

    prep_kernel<<<33, 256, 0, stream>>>(x, mu, ws);
    rsoft_kernel<<<128, 256, 0, stream>>>(x, prec, ws);
    fein_kernel<<<256, 256, 0, stream>>>(x, ws);
    final_kernel<<<128, 256, 0, stream>>>(mu, ws, out);
}

// Round 2
// 41.068 us; speedup vs baseline: 1.5686x; 1.5686x over previous
//
#include <hip/hip_runtime.h>

// Problem constants
#define BB 8
#define FF 256
#define TT 1024
#define CC 64
#define TCHUNK 16
#define NTILE 64            // TT / TCHUNK
#define NBLK (BB * NTILE)   // 512 fused blocks
constexpr float EPS = 1e-9f;

// ws layout (float offsets)
#define WS_MU2   0                    // [64]
#define WS_P2    64                   // [64]
#define WS_NPART 128                  // [512][64]
#define WS_FPART 32896                // [512][64][256]

// ---------------------------------------------------------------------------
// prep: mu2[c] = sum_f mu[c][f]^2 ; p2[c] = prec[c]^2.  One tiny block.
// ---------------------------------------------------------------------------
__global__ __launch_bounds__(256) void prep_kernel(const float* __restrict__ mu,
                                                   const float* __restrict__ prec,
                                                   float* __restrict__ ws) {
    const int tid = threadIdx.x;
    const int c = tid >> 2, q = tid & 3;          // 4 lanes per c
    const float* mp = mu + c * FF + q * 64;
    float s = 0.f;
    #pragma unroll
    for (int i = 0; i < 16; ++i) {
        float4 v = *(const float4*)(mp + i * 4);
        s += v.x * v.x + v.y * v.y + v.z * v.z + v.w * v.w;
    }
    s += __shfl_xor(s, 1);
    s += __shfl_xor(s, 2);
    if (q == 0) ws[WS_MU2 + c] = s;
    if (tid < CC) { float p = prec[tid]; ws[WS_P2 + tid] = p * p; }
}

// ---------------------------------------------------------------------------
// fused: per (b, 16-t chunk): stage x^T tile, x2, xmu (K-split-4 over f),
// softmax over c, F-partial GEMM, write F/N partials. No atomics.
// ---------------------------------------------------------------------------
#define XS_STRIDE 260   // 1040 B row: 16B-aligned, 8 distinct banks for tr rows
#define SR_STRIDE 68    // 272 B: 16B-aligned
#define RL_STRIDE 68

__global__ __launch_bounds__(256) void fused_kernel(const float* __restrict__ x,
                                                    const float* __restrict__ mu,
                                                    float* __restrict__ ws) {
    __shared__ __align__(16) float xt[TCHUNK][XS_STRIDE];       // [t][f]
    __shared__ __align__(16) float Sred[4][TCHUNK][SR_STRIDE];  // K-split partials
    __shared__ __align__(16) float rl[TCHUNK][RL_STRIDE];       // r[t][c]
    __shared__ float x2s[TCHUNK];
    __shared__ float mu2s[CC], p2s[CC];

    const int tid = threadIdx.x;
    const int b    = blockIdx.x >> 6;
    const int tile = blockIdx.x & 63;
    const int t0   = tile * TCHUNK;
    const float* xb = x + (size_t)b * FF * TT;

    // ---- stage x[b][:, t0..t0+16) transposed into xt[t][f] ----
    #pragma unroll
    for (int i = 0; i < 4; ++i) {
        const int id = i * 256 + tid;
        const int f = id >> 2, seg = id & 3;
        float4 v = *(const float4*)(xb + f * TT + t0 + seg * 4);
        xt[seg * 4 + 0][f] = v.x;
        xt[seg * 4 + 1][f] = v.y;
        xt[seg * 4 + 2][f] = v.z;
        xt[seg * 4 + 3][f] = v.w;
    }
    if (tid < CC) { mu2s[tid] = ws[WS_MU2 + tid]; p2s[tid] = ws[WS_P2 + tid]; }
    __syncthreads();

    // ---- x2[t] = sum_f xt[t][f]^2  (16 lanes per row, strided f) ----
    {
        const int t = tid >> 4, kk = tid & 15;
        float s = 0.f;
        #pragma unroll
        for (int q = 0; q < 16; ++q) { float v = xt[t][kk + 16 * q]; s += v * v; }
        s += __shfl_xor(s, 1);
        s += __shfl_xor(s, 2);
        s += __shfl_xor(s, 4);
        s += __shfl_xor(s, 8);
        if (kk == 0) x2s[t] = s;
    }
    __syncthreads();

    // ---- phase 1: xmu, K-split by wave (wave g owns f in [g*64, g*64+64)) ----
    {
        const int g = tid >> 6;            // wave id
        const int lane = tid & 63;
        const int tr = lane & 7;           // t = tr, tr+8
        const int tcc = lane >> 3;         // c = tcc*8 .. +8
        const int c0 = tcc * 8;
        float acc[2][8];
        #pragma unroll
        for (int i = 0; i < 2; ++i)
            #pragma unroll
            for (int j = 0; j < 8; ++j) acc[i][j] = 0.f;

        const float* mupt = mu + (size_t)c0 * FF + g * 64;
        #pragma unroll 4
        for (int kk = 0; kk < 16; ++kk) {
            const int f4 = g * 64 + kk * 4;
            float4 xv0 = *(const float4*)&xt[tr][f4];
            float4 xv1 = *(const float4*)&xt[tr + 8][f4];
            #pragma unroll
            for (int j = 0; j < 8; ++j) {
                float4 mv = *(const float4*)(mupt + j * FF + kk * 4);
                acc[0][j] += xv0.x * mv.x + xv0.y * mv.y + xv0.z * mv.z + xv0.w * mv.w;
                acc[1][j] += xv1.x * mv.x + xv1.y * mv.y + xv1.z * mv.z + xv1.w * mv.w;
            }
        }
        #pragma unroll
        for (int i = 0; i < 2; ++i) {
            *(float4*)&Sred[g][tr + 8 * i][c0] =
                make_float4(acc[i][0], acc[i][1], acc[i][2], acc[i][3]);
            *(float4*)&Sred[g][tr + 8 * i][c0 + 4] =
                make_float4(acc[i][4], acc[i][5], acc[i][6], acc[i][7]);
        }
    }
    __syncthreads();

    // ---- reduce K-split + llk + softmax over c (16 lanes per t-row) ----
    {
        const int t = tid >> 4, kk = tid & 15;
        const int c4 = kk * 4;
        float Sx = 0.f, Sy = 0.f, Sz = 0.f, Sw = 0.f;
        #pragma unroll
        for (int gg = 0; gg < 4; ++gg) {
            float4 v = *(const float4*)&Sred[gg][t][c4];
            Sx += v.x; Sy += v.y; Sz += v.z; Sw += v.w;
        }
        const float x2v = x2s[t];
        float l0 = -p2s[c4 + 0] * (x2v - 2.f * Sx + mu2s[c4 + 0]);
        float l1 = -p2s[c4 + 1] * (x2v - 2.f * Sy + mu2s[c4 + 1]);
        float l2 = -p2s[c4 + 2] * (x2v - 2.f * Sz + mu2s[c4 + 2]);
        float l3 = -p2s[c4 + 3] * (x2v - 2.f * Sw + mu2s[c4 + 3]);
        float m = fmaxf(fmaxf(l0, l1), fmaxf(l2, l3));
        m = fmaxf(m, __shfl_xor(m, 1));
        m = fmaxf(m, __shfl_xor(m, 2));
        m = fmaxf(m, __shfl_xor(m, 4));
        m = fmaxf(m, __shfl_xor(m, 8));
        float e0 = __expf(l0 - m), e1 = __expf(l1 - m);
        float e2 = __expf(l2 - m), e3 = __expf(l3 - m);
        float sum = e0 + e1 + e2 + e3;
        sum += __shfl_xor(sum, 1);
        sum += __shfl_xor(sum, 2);
        sum += __shfl_xor(sum, 4);
        sum += __shfl_xor(sum, 8);
        const float inv = 1.f / sum;
        *(float4*)&rl[t][c4] = make_float4(e0 * inv, e1 * inv, e2 * inv, e3 * inv);
    }
    __syncthreads();

    // ---- N partial (first 64 lanes) ----
    if (tid < CC) {
        float ns = 0.f;
        #pragma unroll
        for (int t = 0; t < TCHUNK; ++t) ns += rl[t][tid];
        ws[WS_NPART + (size_t)blockIdx.x * CC + tid] = ns;
    }

    // ---- phase 2: F_p[c][f] = sum_t r[t][c] * x[t][f] ----
    {
        const int fc = tid & 15;       // f = fc*4 + 64*q  (strided: 2-way banks)
        const int cc = tid >> 4;
        const int c0 = cc * 4;
        float a2[4][4][4];             // [j][q][e]
        #pragma unroll
        for (int j = 0; j < 4; ++j)
            #pragma unroll
            for (int q = 0; q < 4; ++q)
                #pragma unroll
                for (int e = 0; e < 4; ++e) a2[j][q][e] = 0.f;

        #pragma unroll 4
        for (int t = 0; t < TCHUNK; ++t) {
            float4 rv = *(const float4*)&rl[t][c0];
            #pragma unroll
            for (int q = 0; q < 4; ++q) {
                float4 xv = *(const float4*)&xt[t][fc * 4 + 64 * q];
                a2[0][q][0] += rv.x * xv.x; a2[0][q][1] += rv.x * xv.y;
                a2[0][q][2] += rv.x * xv.z; a2[0][q][3] += rv.x * xv.w;
                a2[1][q][0] += rv.y * xv.x; a2[1][q][1] += rv.y * xv.y;
                a2[1][q][2] += rv.y * xv.z; a2[1][q][3] += rv.y * xv.w;
                a2[2][q][0] += rv.z * xv.x; a2[2][q][1] += rv.z * xv.y;
                a2[2][q][2] += rv.z * xv.z; a2[2][q][3] += rv.z * xv.w;
                a2[3][q][0] += rv.w * xv.x; a2[3][q][1] += rv.w * xv.y;
                a2[3][q][2] += rv.w * xv.z; a2[3][q][3] += rv.w * xv.w;
            }
        }
        float* fp = ws + WS_FPART + (size_t)blockIdx.x * CC * FF;
        #pragma unroll
        for (int j = 0; j < 4; ++j)
            #pragma unroll
            for (int q = 0; q < 4; ++q)
                *(float4*)(fp + (c0 + j) * FF + fc * 4 + 64 * q) =
                    make_float4(a2[j][q][0], a2[j][q][1], a2[j][q][2], a2[j][q][3]);
    }
}

// ---------------------------------------------------------------------------
// final: out[b][c][f] = (sum_tiles Fp - Nraw*mu) / (Nraw + eps)
// grid = 512 blocks (b,c), 256 threads (f)
// ---------------------------------------------------------------------------
__global__ __launch_bounds__(256) void final_kernel(const float* __restrict__ mu,
                                                    const float* __restrict__ ws,
                                                    float* __restrict__ out) {
    const int bid = blockIdx.x;
    const int b = bid >> 6, c = bid & 63;
    const int f = threadIdx.x;
    const float* fp = ws + WS_FPART + (size_t)(b * NTILE) * CC * FF + c * FF + f;
    float s = 0.f;
    #pragma unroll 8
    for (int tile = 0; tile < NTILE; ++tile) s += fp[(size_t)tile * CC * FF];
    const float* np = ws + WS_NPART + (size_t)(b * NTILE) * CC + c;
    float nr = 0.f;
    #pragma unroll 8
    for (int tile = 0; tile < NTILE; ++tile) nr += np[tile * CC];
    const float mv = mu[c * FF + f];
    out[((size_t)b * CC + c) * FF + f] = (s - nr * mv) / (nr + EPS);
}

extern "C" void kernel_launch(void* const* d_in, const int* in_sizes, int n_in,
                              void* d_out, int out_size, void* d_ws, size_t ws_size,
                              hipStream_t stream) {
    const float* x    = (const float*)d_in[0];
    const float* mu   = (const float*)d_in[1];
    const float* prec = (const float*)d_in[2];
    float* out = (float*)d_out;
    float* ws  = (float*)d_ws;

    prep_kernel<<<1, 256, 0, stream>>>(mu, prec, ws);
    fused_kernel<<<NBLK, 256, 0, stream>>>(x, mu, ws);
    final_kernel<<<NBLK, 256, 0, stream>>>(mu, ws, out);
}

// Round 3
// 33.440 us; speedup vs baseline: 1.9264x; 1.2281x over previous
//
#include <hip/hip_runtime.h>

// Problem constants
#define BB 8
#define FF 256
#define TT 1024
#define CC 64
constexpr float EPS = 1e-9f;

// pass A tiling
#define TCHUNK 16
#define NTILE 64            // TT / TCHUNK
// pass B tiling
#define BT 64               // t-chunk
#define NTQ 16              // TT / BT
#define BCF (BB * CC * FF)  // 131072

// ws layout (float offsets)
#define WS_R   0            // r[B][C][T]        524288
#define WS_NP  524288       // Npart[512][64]     32768
#define WS_FP  557056       // Fpart[16][B][C][F] 2097152

// ---------------------------------------------------------------------------
// pass A: per (b, 16-t chunk): mu2/p2 inline, stage x^T, x2, xmu (K-split by
// wave), softmax over c, write r[b][c][t] + N partials. 512 blocks.
// ---------------------------------------------------------------------------
__global__ __launch_bounds__(256) void passA_kernel(const float* __restrict__ x,
                                                    const float* __restrict__ mu,
                                                    const float* __restrict__ prec,
                                                    float* __restrict__ ws) {
    __shared__ __align__(16) float xt[TCHUNK][260];      // [t][f]
    __shared__ __align__(16) float Sred[4][TCHUNK][68];  // K-split partials
    __shared__ __align__(16) float rl[TCHUNK][68];       // r[t][c]
    __shared__ float x2s[TCHUNK];
    __shared__ float mu2s[CC], p2s[CC];

    const int tid = threadIdx.x;
    const int b    = blockIdx.x >> 6;
    const int tile = blockIdx.x & 63;
    const int t0   = tile * TCHUNK;
    const float* xb = x + (size_t)b * FF * TT;

    // ---- mu2[c], p2[c] inline (replaces prep kernel) ----
    {
        const int c = tid >> 2, q = tid & 3;
        const float* mp = mu + c * FF + q * 64;
        float s = 0.f;
        #pragma unroll
        for (int i = 0; i < 16; ++i) {
            float4 v = *(const float4*)(mp + i * 4);
            s += v.x * v.x + v.y * v.y + v.z * v.z + v.w * v.w;
        }
        s += __shfl_xor(s, 1);
        s += __shfl_xor(s, 2);
        if (q == 0) mu2s[c] = s;
        if (tid < CC) { float p = prec[tid]; p2s[tid] = p * p; }
    }

    // ---- stage x[b][:, t0..t0+16) transposed into xt[t][f] ----
    #pragma unroll
    for (int i = 0; i < 4; ++i) {
        const int id = i * 256 + tid;
        const int f = id >> 2, seg = id & 3;
        float4 v = *(const float4*)(xb + f * TT + t0 + seg * 4);
        xt[seg * 4 + 0][f] = v.x;
        xt[seg * 4 + 1][f] = v.y;
        xt[seg * 4 + 2][f] = v.z;
        xt[seg * 4 + 3][f] = v.w;
    }
    __syncthreads();

    // ---- x2[t] ----
    {
        const int t = tid >> 4, kk = tid & 15;
        float s = 0.f;
        #pragma unroll
        for (int q = 0; q < 16; ++q) { float v = xt[t][kk + 16 * q]; s += v * v; }
        s += __shfl_xor(s, 1);
        s += __shfl_xor(s, 2);
        s += __shfl_xor(s, 4);
        s += __shfl_xor(s, 8);
        if (kk == 0) x2s[t] = s;
    }
    __syncthreads();

    // ---- xmu GEMM, K-split by wave (wave g owns f in [g*64, g*64+64)) ----
    {
        const int g = tid >> 6;
        const int lane = tid & 63;
        const int tr = lane & 7;
        const int c0 = (lane >> 3) * 8;
        float acc[2][8];
        #pragma unroll
        for (int i = 0; i < 2; ++i)
            #pragma unroll
            for (int j = 0; j < 8; ++j) acc[i][j] = 0.f;

        const float* mupt = mu + (size_t)c0 * FF + g * 64;
        #pragma unroll 4
        for (int kk = 0; kk < 16; ++kk) {
            const int f4 = g * 64 + kk * 4;
            float4 xv0 = *(const float4*)&xt[tr][f4];
            float4 xv1 = *(const float4*)&xt[tr + 8][f4];
            #pragma unroll
            for (int j = 0; j < 8; ++j) {
                float4 mv = *(const float4*)(mupt + j * FF + kk * 4);
                acc[0][j] += xv0.x * mv.x + xv0.y * mv.y + xv0.z * mv.z + xv0.w * mv.w;
                acc[1][j] += xv1.x * mv.x + xv1.y * mv.y + xv1.z * mv.z + xv1.w * mv.w;
            }
        }
        #pragma unroll
        for (int i = 0; i < 2; ++i) {
            *(float4*)&Sred[g][tr + 8 * i][c0] =
                make_float4(acc[i][0], acc[i][1], acc[i][2], acc[i][3]);
            *(float4*)&Sred[g][tr + 8 * i][c0 + 4] =
                make_float4(acc[i][4], acc[i][5], acc[i][6], acc[i][7]);
        }
    }
    __syncthreads();

    // ---- reduce K-split + llk + softmax over c ----
    {
        const int t = tid >> 4, kk = tid & 15;
        const int c4 = kk * 4;
        float Sx = 0.f, Sy = 0.f, Sz = 0.f, Sw = 0.f;
        #pragma unroll
        for (int gg = 0; gg < 4; ++gg) {
            float4 v = *(const float4*)&Sred[gg][t][c4];
            Sx += v.x; Sy += v.y; Sz += v.z; Sw += v.w;
        }
        const float x2v = x2s[t];
        float l0 = -p2s[c4 + 0] * (x2v - 2.f * Sx + mu2s[c4 + 0]);
        float l1 = -p2s[c4 + 1] * (x2v - 2.f * Sy + mu2s[c4 + 1]);
        float l2 = -p2s[c4 + 2] * (x2v - 2.f * Sz + mu2s[c4 + 2]);
        float l3 = -p2s[c4 + 3] * (x2v - 2.f * Sw + mu2s[c4 + 3]);
        float m = fmaxf(fmaxf(l0, l1), fmaxf(l2, l3));
        m = fmaxf(m, __shfl_xor(m, 1));
        m = fmaxf(m, __shfl_xor(m, 2));
        m = fmaxf(m, __shfl_xor(m, 4));
        m = fmaxf(m, __shfl_xor(m, 8));
        float e0 = __expf(l0 - m), e1 = __expf(l1 - m);
        float e2 = __expf(l2 - m), e3 = __expf(l3 - m);
        float sum = e0 + e1 + e2 + e3;
        sum += __shfl_xor(sum, 1);
        sum += __shfl_xor(sum, 2);
        sum += __shfl_xor(sum, 4);
        sum += __shfl_xor(sum, 8);
        const float inv = 1.f / sum;
        *(float4*)&rl[t][c4] = make_float4(e0 * inv, e1 * inv, e2 * inv, e3 * inv);
    }
    __syncthreads();

    // ---- N partial ----
    if (tid < CC) {
        float ns = 0.f;
        #pragma unroll
        for (int t = 0; t < TCHUNK; ++t) ns += rl[t][tid];
        ws[WS_NP + (size_t)blockIdx.x * CC + tid] = ns;
    }

    // ---- r writeout [b][c][t] ----
    {
        const int c = tid >> 2, seg = tid & 3;
        float4 v;
        v.x = rl[seg * 4 + 0][c];
        v.y = rl[seg * 4 + 1][c];
        v.z = rl[seg * 4 + 2][c];
        v.w = rl[seg * 4 + 3][c];
        *(float4*)(ws + WS_R + ((size_t)b * CC + c) * TT + t0 + seg * 4) = v;
    }
}

// ---------------------------------------------------------------------------
// pass B: Fpart[tq][b][c][f0..f0+64) = sum_{t in chunk} r[b][c][t]*x[b][f][t]
// grid 512: b(8) x fsl(4) x tq(16). 256 threads, 4c x 4f per thread.
// ---------------------------------------------------------------------------
__global__ __launch_bounds__(256) void passB_kernel(const float* __restrict__ x,
                                                    float* __restrict__ ws) {
    __shared__ __align__(16) float xs[BT][68];   // [t][f']
    __shared__ __align__(16) float rs[CC][68];   // [c][t']
    const int tid = threadIdx.x;
    const int bid = blockIdx.x;
    const int b   = bid >> 6;
    const int fsl = (bid >> 4) & 3;
    const int tq  = bid & 15;
    const int f0  = fsl * 64;
    const int t0  = tq * BT;
    const float* xb = x + (size_t)b * FF * TT;
    const float* rb = ws + WS_R + (size_t)b * CC * TT;

    #pragma unroll
    for (int it = 0; it < 4; ++it) {
        const int id = it * 256 + tid;
        {   // x tile: transpose into xs[t][f']
            const int ff = id >> 4, seg = id & 15;
            float4 v = *(const float4*)(xb + (f0 + ff) * TT + t0 + seg * 4);
            xs[seg * 4 + 0][ff] = v.x;
            xs[seg * 4 + 1][ff] = v.y;
            xs[seg * 4 + 2][ff] = v.z;
            xs[seg * 4 + 3][ff] = v.w;
        }
        {   // r tile: direct copy rs[c][t']
            const int c = id >> 4, cs = id & 15;
            float4 v = *(const float4*)(rb + (size_t)c * TT + t0 + cs * 4);
            *(float4*)&rs[c][cs * 4] = v;
        }
    }
    __syncthreads();

    const int fi = tid & 15, cg = tid >> 4;
    float acc[4][4];
    #pragma unroll
    for (int j = 0; j < 4; ++j)
        #pragma unroll
        for (int e = 0; e < 4; ++e) acc[j][e] = 0.f;

    #pragma unroll 8
    for (int t = 0; t < BT; ++t) {
        float4 xv = *(const float4*)&xs[t][fi * 4];
        #pragma unroll
        for (int j = 0; j < 4; ++j) {
            float rv = rs[cg * 4 + j][t];
            acc[j][0] += rv * xv.x;
            acc[j][1] += rv * xv.y;
            acc[j][2] += rv * xv.z;
            acc[j][3] += rv * xv.w;
        }
    }

    float* fp = ws + WS_FP + (size_t)tq * BCF + (size_t)b * CC * FF;
    #pragma unroll
    for (int j = 0; j < 4; ++j)
        *(float4*)(fp + (cg * 4 + j) * FF + f0 + fi * 4) =
            make_float4(acc[j][0], acc[j][1], acc[j][2], acc[j][3]);
}

// ---------------------------------------------------------------------------
// final: out[b][c][f] = (sum_p Fp - N*mu) / (N + eps).  grid 512 = (b,c).
// ---------------------------------------------------------------------------
__global__ __launch_bounds__(256) void final_kernel(const float* __restrict__ mu,
                                                    const float* __restrict__ ws,
                                                    float* __restrict__ out) {
    const int b = blockIdx.x >> 6, c = blockIdx.x & 63;
    const int f = threadIdx.x;
    float nr = 0.f;
    const float* np = ws + WS_NP + (size_t)b * NTILE * CC + c;
    #pragma unroll
    for (int tile = 0; tile < NTILE; ++tile) nr += np[tile * CC];
    const float* fp = ws + WS_FP + (size_t)b * CC * FF + c * FF + f;
    float s = 0.f;
    #pragma unroll
    for (int p = 0; p < NTQ; ++p) s += fp[(size_t)p * BCF];
    out[((size_t)b * CC + c) * FF + f] = (s - nr * mu[c * FF + f]) / (nr + EPS);
}

extern "C" void kernel_launch(void* const* d_in, const int* in_sizes, int n_in,
                              void* d_out, int out_size, void* d_ws, size_t ws_size,
                              hipStream_t stream) {
    const float* x    = (const float*)d_in[0];
    const float* mu   = (const float*)d_in[1];
    const float* prec = (const float*)d_in[2];
    float* out = (float*)d_out;
    float* ws  = (float*)d_ws;

    passA_kernel<<<512, 256, 0, stream>>>(x, mu, prec, ws);
    passB_kernel<<<512, 256, 0, stream>>>(x, ws);
    final_kernel<<<512, 256, 0, stream>>>(mu, ws, out);
}